// Round 3
// baseline (131.345 us; speedup 1.0000x reference)
//
#include <hip/hip_runtime.h>
#include <hip/hip_bf16.h>

namespace {
constexpr int B   = 16;
constexpr int NS  = 1000;
constexpr int IN  = 128;
constexpr int OUT = 128;
constexpr int K   = 256;   // IN + OUT
constexpr int XHP = 260;   // padded xh row stride (floats): 4-bgroup reads hit distinct banks

__device__ __forceinline__ float fsigmoid(float x) {
  return 1.0f / (1.0f + __expf(-x));
}
__device__ __forceinline__ float ftanh(float x) {
  return 2.0f / (1.0f + __expf(-2.0f * x)) - 1.0f;
}

__global__ __launch_bounds__(256, 4) void lstm_kernel(
    const float* __restrict__ xt, const float* __restrict__ hidden,
    const float* __restrict__ ct_1,
    const float* __restrict__ Wi, const float* __restrict__ bi,
    const float* __restrict__ Wo, const float* __restrict__ bo,
    const float* __restrict__ Wf, const float* __restrict__ bfp,
    const float* __restrict__ Wc, const float* __restrict__ bc,
    float* __restrict__ out) {
  // Phase 1 view: xh[16][XHP=260] fp32 (16.6 KiB). Phase 2 view: gbuf[4][16][128] fp32 (32 KiB).
  __shared__ float smem[4 * B * OUT];  // 8192 floats = 32 KiB (union covers both phases)

  const int n = blockIdx.x;
  const int tid = threadIdx.x;

  // ---- stage xh = concat(xt[:, n, :], hidden[0, n, :]) into LDS (padded stride) ----
  #pragma unroll
  for (int r = 0; r < 2; ++r) {
    const int idx = tid + (r << 8);   // 0..511
    const int b = idx >> 5;           // 0..15
    const int j = (idx & 31) << 2;    // 0,4,...,124
    const float4 xv = *reinterpret_cast<const float4*>(
        xt + ((size_t)b * NS + n) * IN + j);
    *reinterpret_cast<float4*>(&smem[b * XHP + j]) = xv;
    const float4 hv = *reinterpret_cast<const float4*>(
        hidden + (size_t)n * OUT + j);
    *reinterpret_cast<float4*>(&smem[b * XHP + IN + j]) = hv;
  }
  __syncthreads();

  const int g  = tid >> 6;         // gate 0..3 (wave-uniform: one gate per wave)
  const int q  = (tid >> 4) & 3;   // batch group: rows q*4 .. q*4+3
  const int cl = tid & 15;         // column group: cols cl*8 .. cl*8+7

  const float* Wg = (g == 0) ? Wi : (g == 1) ? Wo : (g == 2) ? Wf : Wc;
  const float* bg = (g == 0) ? bi : (g == 1) ? bo : (g == 2) ? bfp : bc;
  const float* wp = Wg + (size_t)n * (K * OUT) + cl * 8;

  float acc[4][8];
  #pragma unroll
  for (int bi2 = 0; bi2 < 4; ++bi2)
    #pragma unroll
    for (int ci = 0; ci < 8; ++ci) acc[bi2][ci] = 0.f;

  #pragma unroll 2
  for (int k = 0; k < K; k += 4) {
    float4 w[4][2];
    #pragma unroll
    for (int kk = 0; kk < 4; ++kk) {
      w[kk][0] = *reinterpret_cast<const float4*>(wp + (size_t)(k + kk) * OUT);
      w[kk][1] = *reinterpret_cast<const float4*>(wp + (size_t)(k + kk) * OUT + 4);
    }
    #pragma unroll
    for (int bi2 = 0; bi2 < 4; ++bi2) {
      const float4 x = *reinterpret_cast<const float4*>(
          &smem[(q * 4 + bi2) * XHP + k]);  // one b128 read feeds 32 FMAs
      #pragma unroll
      for (int ci = 0; ci < 4; ++ci) {
        acc[bi2][ci]     = fmaf(x.x, (&w[0][0].x)[ci], acc[bi2][ci]);
        acc[bi2][ci]     = fmaf(x.y, (&w[1][0].x)[ci], acc[bi2][ci]);
        acc[bi2][ci]     = fmaf(x.z, (&w[2][0].x)[ci], acc[bi2][ci]);
        acc[bi2][ci]     = fmaf(x.w, (&w[3][0].x)[ci], acc[bi2][ci]);
        acc[bi2][ci + 4] = fmaf(x.x, (&w[0][1].x)[ci], acc[bi2][ci + 4]);
        acc[bi2][ci + 4] = fmaf(x.y, (&w[1][1].x)[ci], acc[bi2][ci + 4]);
        acc[bi2][ci + 4] = fmaf(x.z, (&w[2][1].x)[ci], acc[bi2][ci + 4]);
        acc[bi2][ci + 4] = fmaf(x.w, (&w[3][1].x)[ci], acc[bi2][ci + 4]);
      }
    }
  }

  // bias for this lane's 8 columns
  float bias[8];
  #pragma unroll
  for (int ci = 0; ci < 8; ++ci) bias[ci] = bg[(size_t)n * OUT + cl * 8 + ci];

  __syncthreads();  // all xh reads done; safe to repurpose smem as gbuf
  #pragma unroll
  for (int bi2 = 0; bi2 < 4; ++bi2) {
    const int b = q * 4 + bi2;
    float4 v0, v1;
    v0.x = acc[bi2][0] + bias[0]; v0.y = acc[bi2][1] + bias[1];
    v0.z = acc[bi2][2] + bias[2]; v0.w = acc[bi2][3] + bias[3];
    v1.x = acc[bi2][4] + bias[4]; v1.y = acc[bi2][5] + bias[5];
    v1.z = acc[bi2][6] + bias[6]; v1.w = acc[bi2][7] + bias[7];
    *reinterpret_cast<float4*>(&smem[((g * B + b) << 7) + cl * 8])     = v0;
    *reinterpret_cast<float4*>(&smem[((g * B + b) << 7) + cl * 8 + 4]) = v1;
  }
  __syncthreads();

  // ---- combine gates, write ht and ct (fp32 outputs) ----
  const size_t nbase = (size_t)n * OUT;
  #pragma unroll
  for (int r = 0; r < 8; ++r) {
    const int p = tid + (r << 8);  // 0..2047
    const int b = p >> 7;
    const int o = p & 127;
    const float gi = smem[((0 * B + b) << 7) + o];
    const float go = smem[((1 * B + b) << 7) + o];
    const float gf = smem[((2 * B + b) << 7) + o];
    const float gc = smem[((3 * B + b) << 7) + o];
    const float it = fsigmoid(gi);
    const float ot = fsigmoid(go);
    const float ft = fsigmoid(gf);
    const float ch = ftanh(gc);
    const float cp = ct_1[nbase + o];
    const float ct = ft * cp + it * ch;
    const float ht = ot * ftanh(ct);
    const size_t oidx = (size_t)b * ((size_t)NS * OUT) + nbase + o;
    out[oidx] = ht;                              // ht
    out[(size_t)B * NS * OUT + oidx] = ct;       // ct
  }
}
}  // namespace

extern "C" void kernel_launch(void* const* d_in, const int* in_sizes, int n_in,
                              void* d_out, int out_size, void* d_ws, size_t ws_size,
                              hipStream_t stream) {
  const float* xt     = (const float*)d_in[0];
  const float* hidden = (const float*)d_in[1];
  const float* ct_1   = (const float*)d_in[2];
  const float* Wi     = (const float*)d_in[3];
  const float* bi     = (const float*)d_in[4];
  const float* Wo     = (const float*)d_in[5];
  const float* bo     = (const float*)d_in[6];
  const float* Wf     = (const float*)d_in[7];
  const float* bf     = (const float*)d_in[8];
  const float* Wc     = (const float*)d_in[9];
  const float* bc     = (const float*)d_in[10];

  lstm_kernel<<<NS, 256, 0, stream>>>(xt, hidden, ct_1, Wi, bi, Wo, bo,
                                      Wf, bf, Wc, bc,
                                      (float*)d_out);
}

// Round 5
// 123.669 us; speedup vs baseline: 1.0621x; 1.0621x over previous
//
#include <hip/hip_runtime.h>
#include <hip/hip_bf16.h>

namespace {
constexpr int B   = 16;
constexpr int NS  = 1000;
constexpr int IN  = 128;
constexpr int OUT = 128;
constexpr int K   = 256;   // IN + OUT
constexpr int XHP = 260;   // padded xh row stride (floats); 260*4B = 65*16B keeps float4 alignment

__device__ __forceinline__ float fsigmoid(float x) {
  return 1.0f / (1.0f + __expf(-x));
}
__device__ __forceinline__ float ftanh(float x) {
  return 2.0f / (1.0f + __expf(-2.0f * x)) - 1.0f;
}

__global__ __launch_bounds__(256, 4) void lstm_kernel(
    const float* __restrict__ xt, const float* __restrict__ hidden,
    const float* __restrict__ ct_1,
    const float* __restrict__ Wi, const float* __restrict__ bi,
    const float* __restrict__ Wo, const float* __restrict__ bo,
    const float* __restrict__ Wf, const float* __restrict__ bfp,
    const float* __restrict__ Wc, const float* __restrict__ bc,
    float* __restrict__ out) {
  // Phase 1 view: xh[16][XHP] fp32 (16.6 KiB). Phase 2 view: gbuf[4][16][128] fp32 (32 KiB).
  __shared__ float smem[4 * B * OUT];

  const int n = blockIdx.x;
  const int tid = threadIdx.x;

  // ---- stage xh = concat(xt[:, n, :], hidden[0, n, :]) into LDS ----
  #pragma unroll
  for (int r = 0; r < 2; ++r) {
    const int idx = tid + (r << 8);   // 0..511
    const int b = idx >> 5;           // 0..15
    const int j = (idx & 31) << 2;    // 0,4,...,124
    const float4 xv = *reinterpret_cast<const float4*>(
        xt + ((size_t)b * NS + n) * IN + j);
    *reinterpret_cast<float4*>(&smem[b * XHP + j]) = xv;
    const float4 hv = *reinterpret_cast<const float4*>(
        hidden + (size_t)n * OUT + j);
    *reinterpret_cast<float4*>(&smem[b * XHP + IN + j]) = hv;
  }
  __syncthreads();

  const int g    = tid >> 6;        // gate 0..3 (one wave per gate)
  const int lane = tid & 63;
  const int kc   = lane >> 5;       // k-half: rows k+kc*4 .. k+kc*4+3 of each 8-row step
  const int cg   = lane & 31;       // column group: cols cg*4 .. cg*4+3

  const float* Wg = (g == 0) ? Wi : (g == 1) ? Wo : (g == 2) ? Wf : Wc;
  const float* bg = (g == 0) ? bi : (g == 1) ? bo : (g == 2) ? bfp : bc;
  const float* wp = Wg + (size_t)n * (K * OUT) + cg * 4;

  float acc[B][4];
  #pragma unroll
  for (int b = 0; b < B; ++b)
    #pragma unroll
    for (int c = 0; c < 4; ++c) acc[b][c] = 0.f;

  // prefetch first step's weights (each instr: 2 rows x 128 cols = 1KB, zero duplication)
  float4 wv[4];
  #pragma unroll
  for (int j = 0; j < 4; ++j)
    wv[j] = *reinterpret_cast<const float4*>(wp + (size_t)(kc * 4 + j) * OUT);

  #pragma unroll 2
  for (int k = 0; k < K; k += 8) {
    const int kn = (k + 8 < K) ? (k + 8) : 0;  // wrap: last prefetch redundant but valid
    float4 nv[4];
    #pragma unroll
    for (int j = 0; j < 4; ++j)
      nv[j] = *reinterpret_cast<const float4*>(wp + (size_t)(kn + kc * 4 + j) * OUT);

    #pragma unroll
    for (int b = 0; b < B; ++b) {
      // one 16B LDS broadcast (2 distinct addrs per wave, conflict-free) feeds 16 FMAs
      const float4 xv = *reinterpret_cast<const float4*>(&smem[b * XHP + k + kc * 4]);
      #pragma unroll
      for (int j = 0; j < 4; ++j) {
        const float xs = (&xv.x)[j];
        acc[b][0] = fmaf(xs, wv[j].x, acc[b][0]);
        acc[b][1] = fmaf(xs, wv[j].y, acc[b][1]);
        acc[b][2] = fmaf(xs, wv[j].z, acc[b][2]);
        acc[b][3] = fmaf(xs, wv[j].w, acc[b][3]);
      }
    }
    #pragma unroll
    for (int j = 0; j < 4; ++j) wv[j] = nv[j];
  }

  // ---- reduce the two k-halves (lane l <-> l^32), both halves end with the sum ----
  #pragma unroll
  for (int b = 0; b < B; ++b)
    #pragma unroll
    for (int c = 0; c < 4; ++c)
      acc[b][c] += __shfl_xor(acc[b][c], 32, 64);

  const float4 bv = *reinterpret_cast<const float4*>(bg + (size_t)n * OUT + cg * 4);

  __syncthreads();  // all xh reads done; safe to repurpose smem as gbuf
  if (kc == 0) {
    #pragma unroll
    for (int b = 0; b < B; ++b) {
      float4 v;
      v.x = acc[b][0] + bv.x; v.y = acc[b][1] + bv.y;
      v.z = acc[b][2] + bv.z; v.w = acc[b][3] + bv.w;
      *reinterpret_cast<float4*>(&smem[((g * B + b) << 7) + cg * 4]) = v;
    }
  }
  __syncthreads();

  // ---- combine gates, write ht and ct (fp32 outputs) ----
  const size_t nbase = (size_t)n * OUT;
  #pragma unroll
  for (int r = 0; r < 8; ++r) {
    const int p = tid + (r << 8);  // 0..2047
    const int b = p >> 7;
    const int o = p & 127;
    const float gi = smem[((0 * B + b) << 7) + o];
    const float go = smem[((1 * B + b) << 7) + o];
    const float gf = smem[((2 * B + b) << 7) + o];
    const float gc = smem[((3 * B + b) << 7) + o];
    const float it = fsigmoid(gi);
    const float ot = fsigmoid(go);
    const float ft = fsigmoid(gf);
    const float ch = ftanh(gc);
    const float cp = ct_1[nbase + o];
    const float ct = ft * cp + it * ch;
    const float ht = ot * ftanh(ct);
    const size_t oidx = (size_t)b * ((size_t)NS * OUT) + nbase + o;
    out[oidx] = ht;                              // ht
    out[(size_t)B * NS * OUT + oidx] = ct;       // ct
  }
}
}  // namespace

extern "C" void kernel_launch(void* const* d_in, const int* in_sizes, int n_in,
                              void* d_out, int out_size, void* d_ws, size_t ws_size,
                              hipStream_t stream) {
  const float* xt     = (const float*)d_in[0];
  const float* hidden = (const float*)d_in[1];
  const float* ct_1   = (const float*)d_in[2];
  const float* Wi     = (const float*)d_in[3];
  const float* bi     = (const float*)d_in[4];
  const float* Wo     = (const float*)d_in[5];
  const float* bo     = (const float*)d_in[6];
  const float* Wf     = (const float*)d_in[7];
  const float* bf     = (const float*)d_in[8];
  const float* Wc     = (const float*)d_in[9];
  const float* bc     = (const float*)d_in[10];

  lstm_kernel<<<NS, 256, 0, stream>>>(xt, hidden, ct_1, Wi, bi, Wo, bo,
                                      Wf, bf, Wc, bc,
                                      (float*)d_out);
}